// Round 2
// baseline (497.898 us; speedup 1.0000x reference)
//
#include <hip/hip_runtime.h>
#include <math.h>

#define NB 32
#define CIN 2048
#define HH 14
#define WW 14
#define HW 196
#define DD 128
#define KK 32
#define NCLASS 1000
#define PWN 10
#define NP 100
#define NPIX 25
#define KD 4096
#define BN_EPS 1e-5f

// ---------------------------------------------------------------------------
// Kernel 1: 1x1 conv as split-K GEMM, fp32, partials via atomicAdd into y.
// grid (4 p-tiles of 64 pixels, 8 k-splits of 256 c, 32 b), block 128.
// Thread tile: 8 d x 8 p. LDS: Xs[32c][64p], Ws[32c][132d] (d-contiguous so
// the compute loop reads W as 2x b128 per c-iter instead of 8 scalar b32 at
// 4-way bank conflict; keeps the loop VALU-bound: ~62 LDS cyc vs 128 FMA cyc).
// ---------------------------------------------------------------------------
__global__ __launch_bounds__(128) void k_conv(const float* __restrict__ x,
                                              const float* __restrict__ cw,
                                              float* __restrict__ y) {
  __shared__ float Xs[32][64];
  __shared__ float Ws[32][132];   // [c][d], pad 132 (16B-aligned rows)
  const int t = threadIdx.x;
  const int hw0 = blockIdx.x * 64;
  const int c0base = blockIdx.y * 256;
  const int b = blockIdx.z;
  const int dg = t >> 3;          // 0..15
  const int pg = t & 7;           // 0..7
  const int d0 = dg * 8;
  const int p0 = pg * 8;

  float acc[8][8];
  #pragma unroll
  for (int j = 0; j < 8; ++j)
    #pragma unroll
    for (int i = 0; i < 8; ++i) acc[j][i] = 0.f;

  for (int ch = 0; ch < 8; ++ch) {
    const int c0 = c0base + ch * 32;
    // stage x tile: 32c x 64p, float4 over p (196%4==0 so f4 never straddles)
    #pragma unroll
    for (int i = 0; i < 4; ++i) {
      int idx = t + 128 * i;            // 0..511
      int c = idx >> 4;
      int p4 = (idx & 15) * 4;
      int hw = hw0 + p4;
      float4 vx = make_float4(0.f, 0.f, 0.f, 0.f);
      if (hw < HW) vx = *(const float4*)&x[((size_t)b * CIN + c0 + c) * HW + hw];
      *(float4*)&Xs[c][p4] = vx;
    }
    // stage w tile: coalesced f4 global read over c, scatter to Ws[c][d]
    #pragma unroll
    for (int i = 0; i < 8; ++i) {
      int idx = t + 128 * i;            // 0..1023
      int d = idx >> 3;
      int c4 = (idx & 7) * 4;
      float4 vw = *(const float4*)&cw[(size_t)d * CIN + c0 + c4];
      Ws[c4 + 0][d] = vw.x; Ws[c4 + 1][d] = vw.y;
      Ws[c4 + 2][d] = vw.z; Ws[c4 + 3][d] = vw.w;
    }
    __syncthreads();
    #pragma unroll 4
    for (int c = 0; c < 32; ++c) {
      float4 xa = *(const float4*)&Xs[c][p0];
      float4 xb = *(const float4*)&Xs[c][p0 + 4];
      float4 wa = *(const float4*)&Ws[c][d0];
      float4 wb = *(const float4*)&Ws[c][d0 + 4];
      float xv[8] = {xa.x, xa.y, xa.z, xa.w, xb.x, xb.y, xb.z, xb.w};
      float wv[8] = {wa.x, wa.y, wa.z, wa.w, wb.x, wb.y, wb.z, wb.w};
      #pragma unroll
      for (int j = 0; j < 8; ++j)
        #pragma unroll
        for (int i = 0; i < 8; ++i) acc[j][i] += wv[j] * xv[i];
    }
    __syncthreads();
  }
  // accumulate partials (8 k-split blocks per output element)
  #pragma unroll
  for (int i = 0; i < 8; ++i) {
    int hw = hw0 + p0 + i;
    if (hw < HW) {
      float* yp = &y[((size_t)b * HW + hw) * DD + d0];
      #pragma unroll
      for (int j = 0; j < 8; ++j) atomicAdd(yp + j, acc[j][i]);
    }
  }
}

// ---------------------------------------------------------------------------
// Kernel 2: conv bias + BN(eval) + ReLU, pointwise in-place on y.
// ---------------------------------------------------------------------------
__global__ __launch_bounds__(256) void k_bnrelu(float* __restrict__ y,
    const float* __restrict__ convb, const float* __restrict__ gamma,
    const float* __restrict__ beta, const float* __restrict__ mean,
    const float* __restrict__ var) {
  int idx = blockIdx.x * 256 + threadIdx.x;   // float4 index, exact grid
  float4 vv = *(float4*)&y[idx * 4];
  int d4 = (idx * 4) & (DD - 1);
  float o[4] = {vv.x, vv.y, vv.z, vv.w};
  #pragma unroll
  for (int j = 0; j < 4; ++j) {
    int d = d4 + j;
    float inv = gamma[d] * rsqrtf(var[d] + BN_EPS);
    float val = (o[j] + convb[d] - mean[d]) * inv + beta[d];
    o[j] = fmaxf(val, 0.f);
  }
  *(float4*)&y[idx * 4] = make_float4(o[0], o[1], o[2], o[3]);
}

// ---------------------------------------------------------------------------
// Kernel 3: soft-VQ encode per (b, patch). Block 256, grid 3200.
// ---------------------------------------------------------------------------
__global__ __launch_bounds__(256) void k_encode(const float* __restrict__ y,
    const float* __restrict__ codewords, const float* __restrict__ scale,
    float* __restrict__ v) {
  __shared__ float Xs[NPIX][132];   // pad 132; 16B aligned rows
  __shared__ float cws[KK][132];    // k-major codewords
  __shared__ float cwT[DD][36];     // d-major codewords, pad 36 (f4-aligned)
  __shared__ float Am[NPIX][36];    // logits -> softmax A
  __shared__ float x2s[NPIX];
  __shared__ float sks[KK];
  __shared__ float c2s[KK];
  __shared__ float scs[KK];
  __shared__ float red[5];

  const int t = threadIdx.x;
  const int bp = blockIdx.x;
  const int b = bp / NP;
  const int p = bp - b * NP;
  const int pi = p / PWN, pj = p - pi * PWN;
  const int wave = t >> 6, lane = t & 63;

  // phase 1: stage patch X (25x128) and codewords (32x128)
  #pragma unroll
  for (int i = 0; i < 4; ++i) {
    int idx = t + 256 * i;            // 0..1023
    if (idx < NPIX * 32) {            // 800 float4s for X
      int n = idx >> 5;
      int d4 = (idx & 31) * 4;
      int di = n / 5, dj = n - di * 5;
      int hw = (pi + di) * WW + (pj + dj);
      float4 vx = *(const float4*)&y[((size_t)b * HW + hw) * DD + d4];
      *(float4*)&Xs[n][d4] = vx;
    }
    int k = idx >> 5;
    int d4 = (idx & 31) * 4;
    float4 vc = *(const float4*)&codewords[k * DD + d4];
    *(float4*)&cws[k][d4] = vc;
  }
  __syncthreads();

  // phase 2: build cwT, x2 per pixel, c2 per codeword, scale
  #pragma unroll
  for (int i = 0; i < 4; ++i) {
    int idx = t + 256 * i;
    int k = idx & 31;
    int d4 = (idx >> 5) * 4;          // 0..124
    float4 vc = *(const float4*)&cws[k][d4];
    cwT[d4 + 0][k] = vc.x; cwT[d4 + 1][k] = vc.y;
    cwT[d4 + 2][k] = vc.z; cwT[d4 + 3][k] = vc.w;
  }
  for (int n = wave; n < NPIX; n += 4) {
    float a = Xs[n][lane];
    float c = Xs[n][lane + 64];
    float r = a * a + c * c;
    #pragma unroll
    for (int off = 32; off; off >>= 1) r += __shfl_xor(r, off, 64);
    if (lane == 0) x2s[n] = r;
  }
  if (t < KK) {
    float s = 0.f;
    #pragma unroll 8
    for (int d4 = 0; d4 < DD; d4 += 4) {
      float4 c4 = *(const float4*)&cws[t][d4];
      s += c4.x * c4.x + c4.y * c4.y + c4.z * c4.z + c4.w * c4.w;
    }
    c2s[t] = s;
    scs[t] = scale[t];
  }
  __syncthreads();

  // phase 3: dist + scaled logits. 2n x 4k register tile; 104 active threads.
  if (t < 104) {
    int n0 = (t >> 3) * 2;
    int k0 = (t & 7) * 4;
    int n1 = n0 + 1;
    bool n1v = (n1 < NPIX);
    int n1c = n1v ? n1 : 0;
    float a0[4] = {0, 0, 0, 0}, a1[4] = {0, 0, 0, 0};
    #pragma unroll 4
    for (int d = 0; d < DD; ++d) {
      float4 cv = *(const float4*)&cwT[d][k0];
      float xv0 = Xs[n0][d];
      float xv1 = Xs[n1c][d];
      a0[0] += xv0 * cv.x; a0[1] += xv0 * cv.y; a0[2] += xv0 * cv.z; a0[3] += xv0 * cv.w;
      a1[0] += xv1 * cv.x; a1[1] += xv1 * cv.y; a1[2] += xv1 * cv.z; a1[3] += xv1 * cv.w;
    }
    float x20 = x2s[n0], x21 = x2s[n1c];
    float4 o0, o1;
    o0.x = scs[k0 + 0] * (x20 - 2.f * a0[0] + c2s[k0 + 0]);
    o0.y = scs[k0 + 1] * (x20 - 2.f * a0[1] + c2s[k0 + 1]);
    o0.z = scs[k0 + 2] * (x20 - 2.f * a0[2] + c2s[k0 + 2]);
    o0.w = scs[k0 + 3] * (x20 - 2.f * a0[3] + c2s[k0 + 3]);
    o1.x = scs[k0 + 0] * (x21 - 2.f * a1[0] + c2s[k0 + 0]);
    o1.y = scs[k0 + 1] * (x21 - 2.f * a1[1] + c2s[k0 + 1]);
    o1.z = scs[k0 + 2] * (x21 - 2.f * a1[2] + c2s[k0 + 2]);
    o1.w = scs[k0 + 3] * (x21 - 2.f * a1[3] + c2s[k0 + 3]);
    *(float4*)&Am[n0][k0] = o0;
    if (n1v) *(float4*)&Am[n1][k0] = o1;
  }
  __syncthreads();

  // phase 4: softmax over k per pixel row
  if (t < NPIX) {
    float m = -1e30f;
    #pragma unroll 8
    for (int k = 0; k < KK; ++k) m = fmaxf(m, Am[t][k]);
    float s = 0.f;
    #pragma unroll 8
    for (int k = 0; k < KK; ++k) {
      float e = __expf(Am[t][k] - m);
      Am[t][k] = e;
      s += e;
    }
    float inv = 1.f / s;
    #pragma unroll 8
    for (int k = 0; k < KK; ++k) Am[t][k] *= inv;
  }
  __syncthreads();

  // phase 5: column sums s[k] = sum_n A[n,k]
  if (t < KK) {
    float s = 0.f;
    #pragma unroll
    for (int n = 0; n < NPIX; ++n) s += Am[n][t];
    sks[t] = s;
  }
  __syncthreads();

  // phase 6: E[k,d] = sum_n A*X - s[k]*cw[k,d]; thread = 8k x 2d tile
  const int dd = (t & 63) * 2;
  const int k0 = (t >> 6) * 8;      // == wave*8, wave-uniform
  float ea[8][2];
  #pragma unroll
  for (int kk = 0; kk < 8; ++kk) { ea[kk][0] = 0.f; ea[kk][1] = 0.f; }
  #pragma unroll 5
  for (int n = 0; n < NPIX; ++n) {
    float2 xv = *(const float2*)&Xs[n][dd];
    float4 q0 = *(const float4*)&Am[n][k0];
    float4 q1 = *(const float4*)&Am[n][k0 + 4];
    float av[8] = {q0.x, q0.y, q0.z, q0.w, q1.x, q1.y, q1.z, q1.w};
    #pragma unroll
    for (int kk = 0; kk < 8; ++kk) {
      ea[kk][0] += av[kk] * xv.x;
      ea[kk][1] += av[kk] * xv.y;
    }
  }
  float ss = 0.f;
  #pragma unroll
  for (int kk = 0; kk < 8; ++kk) {
    int k = k0 + kk;
    float s = sks[k];
    float2 cv = *(const float2*)&cws[k][dd];
    ea[kk][0] -= s * cv.x;
    ea[kk][1] -= s * cv.y;
    ss += ea[kk][0] * ea[kk][0] + ea[kk][1] * ea[kk][1];
  }
  #pragma unroll
  for (int off = 32; off; off >>= 1) ss += __shfl_xor(ss, off, 64);
  if (lane == 0) red[wave] = ss;
  __syncthreads();
  if (t == 0) {
    float tot = red[0] + red[1] + red[2] + red[3];
    red[4] = 1.f / fmaxf(sqrtf(tot), 1e-12f);
  }
  __syncthreads();
  float rn = red[4];
  float* vb = v + (size_t)b * KD;
  #pragma unroll
  for (int kk = 0; kk < 8; ++kk) {
    int k = k0 + kk;
    atomicAdd(&vb[k * DD + dd + 0], ea[kk][0] * rn);
    atomicAdd(&vb[k * DD + dd + 1], ea[kk][1] * rn);
  }
}

// ---------------------------------------------------------------------------
// Kernel 4: classifier out[32,1000] = v @ cls_w^T + cls_b.
// 2 classes per wave (acc[2][32] in regs): halves v re-read traffic vs
// wave-per-class (524MB -> 262MB through L2/L3), and the block's 8 classes
// share v lines via L1. cls_w (16.4MB) read exactly once, coalesced f4.
// ---------------------------------------------------------------------------
__global__ __launch_bounds__(256) void k_cls(const float* __restrict__ v,
    const float* __restrict__ cls_w, const float* __restrict__ cls_b,
    float* __restrict__ out) {
  const int wave = threadIdx.x >> 6;
  const int lane = threadIdx.x & 63;
  const int n0 = blockIdx.x * 8 + wave * 2;   // grid 125 -> classes 0..999
  const float* w0 = cls_w + (size_t)n0 * KD;
  const float* w1 = cls_w + (size_t)(n0 + 1) * KD;
  float acc0[NB], acc1[NB];
  #pragma unroll
  for (int b = 0; b < NB; ++b) { acc0[b] = 0.f; acc1[b] = 0.f; }
  #pragma unroll 2
  for (int i = 0; i < 16; ++i) {
    int kd = i * 256 + lane * 4;
    float4 a4 = *(const float4*)&w0[kd];
    float4 b4 = *(const float4*)&w1[kd];
    #pragma unroll
    for (int b = 0; b < NB; ++b) {
      float4 v4 = *(const float4*)&v[b * KD + kd];
      acc0[b] += a4.x * v4.x + a4.y * v4.y + a4.z * v4.z + a4.w * v4.w;
      acc1[b] += b4.x * v4.x + b4.y * v4.y + b4.z * v4.z + b4.w * v4.w;
    }
  }
  #pragma unroll
  for (int b = 0; b < NB; ++b) {
    float r0 = acc0[b], r1 = acc1[b];
    #pragma unroll
    for (int off = 32; off; off >>= 1) {
      r0 += __shfl_xor(r0, off, 64);
      r1 += __shfl_xor(r1, off, 64);
    }
    if (lane == 0) {
      out[b * NCLASS + n0]     = r0 + cls_b[n0];
      out[b * NCLASS + n0 + 1] = r1 + cls_b[n0 + 1];
    }
  }
}

// ---------------------------------------------------------------------------
extern "C" void kernel_launch(void* const* d_in, const int* in_sizes, int n_in,
                              void* d_out, int out_size, void* d_ws, size_t ws_size,
                              hipStream_t stream) {
  const float* x         = (const float*)d_in[0];
  const float* conv_w    = (const float*)d_in[1];
  const float* conv_b    = (const float*)d_in[2];
  const float* bn_gamma  = (const float*)d_in[3];
  const float* bn_beta   = (const float*)d_in[4];
  const float* bn_mean   = (const float*)d_in[5];
  const float* bn_var    = (const float*)d_in[6];
  const float* codewords = (const float*)d_in[7];
  const float* scale     = (const float*)d_in[8];
  const float* cls_w     = (const float*)d_in[9];
  const float* cls_b     = (const float*)d_in[10];
  float* out = (float*)d_out;

  const size_t YBYTES = (size_t)NB * HW * DD * sizeof(float);   // 3,211,264
  const size_t VBYTES = (size_t)NB * KD * sizeof(float);        //   524,288
  float* y = (float*)d_ws;
  float* v = (float*)((char*)d_ws + YBYTES);

  hipMemsetAsync(y, 0, YBYTES, stream);
  hipMemsetAsync(v, 0, VBYTES, stream);

  k_conv<<<dim3(4, 8, NB), 128, 0, stream>>>(x, conv_w, y);
  k_bnrelu<<<(NB * HW * DD) / (256 * 4), 256, 0, stream>>>(
      y, conv_b, bn_gamma, bn_beta, bn_mean, bn_var);
  k_encode<<<NB * NP, 256, 0, stream>>>(y, codewords, scale, v);
  k_cls<<<NCLASS / 8, 256, 0, stream>>>(v, cls_w, cls_b, out);
}

// Round 6
// 391.988 us; speedup vs baseline: 1.2702x; 1.2702x over previous
//
#include <hip/hip_runtime.h>
#include <math.h>

#define NB 32
#define CIN 2048
#define HH 14
#define WW 14
#define HW 196
#define DD 128
#define KK 32
#define NCLASS 1000
#define PWN 10
#define NP 100
#define NPIX 25
#define KD 4096
#define BN_EPS 1e-5f
#define YELEMS (NB * HW * DD)    // 802816

// ---------------------------------------------------------------------------
// Kernel 0: transpose conv_w [D][CIN] -> w_t [CIN][D] (one-time, ~1 MB).
// ---------------------------------------------------------------------------
__global__ __launch_bounds__(256) void k_wt(const float* __restrict__ cw,
                                            float* __restrict__ wt) {
  __shared__ float T[32][33];
  const int tx = threadIdx.x & 31;
  const int ty = threadIdx.x >> 5;          // 0..7
  const int c0 = blockIdx.x * 32;           // 64 tiles over CIN
  const int d0 = blockIdx.y * 32;           // 4 tiles over D
  #pragma unroll
  for (int k = 0; k < 4; ++k)
    T[ty + 8 * k][tx] = cw[(size_t)(d0 + ty + 8 * k) * CIN + c0 + tx];
  __syncthreads();
  #pragma unroll
  for (int k = 0; k < 4; ++k)
    wt[(size_t)(c0 + ty + 8 * k) * DD + d0 + tx] = T[tx][ty + 8 * k];
}

// ---------------------------------------------------------------------------
// Kernel 1: 1x1 conv, LDS-free register-tiled fp32 GEMM.
// grid (7 p-tiles of 32, nsplit c-splits, 32 b), block 256 (4 waves).
// Thread: 4p x 4d. Per c-iter: 1 x-float4 (L1 broadcast x16 within block,
// HBM-fetched exactly once) + 1 w-float4 (L2-hot) + 16 FMA.
// No LDS, no barriers, no atomics: partials -> y_part[split], plain stores.
// ---------------------------------------------------------------------------
__global__ __launch_bounds__(256) void k_conv(const float* __restrict__ x,
                                              const float* __restrict__ wt,
                                              float* __restrict__ y_part,
                                              int cspl) {
  const int t = threadIdx.x;
  const int pg = t >> 5;                    // 0..7
  const int dg = t & 31;                    // 0..31
  const int p0 = pg * 4;
  const int d0 = dg * 4;
  const int hw0 = blockIdx.x * 32;
  const int s = blockIdx.y;
  const int b = blockIdx.z;
  const int hwp = hw0 + p0;
  const bool valid = (hwp < HW);            // 196%4==0: f4 all-or-nothing
  const int hwc = valid ? hwp : 0;

  const float* xp = x + ((size_t)(b * CIN + s * cspl) * HW + hwc);
  const float* wp = wt + (size_t)(s * cspl) * DD + d0;

  float acc[4][4];
  #pragma unroll
  for (int i = 0; i < 4; ++i)
    #pragma unroll
    for (int j = 0; j < 4; ++j) acc[i][j] = 0.f;

  #pragma unroll 4
  for (int c = 0; c < cspl; ++c) {
    float4 xv = *(const float4*)xp;
    float4 wv = *(const float4*)wp;
    float xa[4] = {xv.x, xv.y, xv.z, xv.w};
    float wa[4] = {wv.x, wv.y, wv.z, wv.w};
    #pragma unroll
    for (int i = 0; i < 4; ++i)
      #pragma unroll
      for (int j = 0; j < 4; ++j) acc[i][j] += xa[i] * wa[j];
    xp += HW;
    wp += DD;
  }
  if (valid) {
    float* yp = y_part + (size_t)s * YELEMS + ((size_t)b * HW + hwp) * DD + d0;
    #pragma unroll
    for (int i = 0; i < 4; ++i)
      *(float4*)(yp + (size_t)i * DD) =
          make_float4(acc[i][0], acc[i][1], acc[i][2], acc[i][3]);
  }
}

// ---------------------------------------------------------------------------
// Kernel 2: reduce nsplit partials + conv bias + BN(eval) + ReLU -> y.
// ---------------------------------------------------------------------------
__global__ __launch_bounds__(256) void k_bnred(const float* __restrict__ y_part,
    float* __restrict__ y, const float* __restrict__ convb,
    const float* __restrict__ gamma, const float* __restrict__ beta,
    const float* __restrict__ mean, const float* __restrict__ var,
    int nsplit) {
  int idx = blockIdx.x * 256 + threadIdx.x;   // float4 index, exact grid
  float4 a = *(const float4*)&y_part[(size_t)idx * 4];
  for (int s = 1; s < nsplit; ++s) {
    float4 p = *(const float4*)&y_part[(size_t)s * YELEMS + (size_t)idx * 4];
    a.x += p.x; a.y += p.y; a.z += p.z; a.w += p.w;
  }
  int d4 = (idx * 4) & (DD - 1);
  float o[4] = {a.x, a.y, a.z, a.w};
  #pragma unroll
  for (int j = 0; j < 4; ++j) {
    int d = d4 + j;
    float inv = gamma[d] * rsqrtf(var[d] + BN_EPS);
    float val = (o[j] + convb[d] - mean[d]) * inv + beta[d];
    o[j] = fmaxf(val, 0.f);
  }
  *(float4*)&y[(size_t)idx * 4] = make_float4(o[0], o[1], o[2], o[3]);
}

// ---------------------------------------------------------------------------
// Kernel 3: soft-VQ encode per (b, patch). Block 256, grid 3200.
// Phase 3+4 fused: 200 active lanes, softmax via width-8 shuffle groups,
// bank-conflict-free LDS patterns throughout.
// ---------------------------------------------------------------------------
__global__ __launch_bounds__(256) void k_encode(const float* __restrict__ y,
    const float* __restrict__ codewords, const float* __restrict__ scale,
    float* __restrict__ v) {
  __shared__ float Xs[NPIX][132];   // row stride 132 (== 4 mod 32 banks)
  __shared__ float cws[KK][132];    // k-major codewords
  __shared__ float cwT[DD][36];     // d-major codewords
  __shared__ float Am[NPIX][36];    // softmax A
  __shared__ float x2s[NPIX];
  __shared__ float sks[KK];
  __shared__ float c2s[KK];
  __shared__ float scs[KK];
  __shared__ float red[5];

  const int t = threadIdx.x;
  const int bp = blockIdx.x;
  const int b = bp / NP;
  const int p = bp - b * NP;
  const int pi = p / PWN, pj = p - pi * PWN;
  const int wave = t >> 6, lane = t & 63;

  // phase 1: stage patch X (25x128) and codewords (32x128)
  #pragma unroll
  for (int i = 0; i < 4; ++i) {
    int idx = t + 256 * i;            // 0..1023
    if (idx < NPIX * 32) {            // 800 float4s for X
      int n = idx >> 5;
      int d4 = (idx & 31) * 4;
      int di = n / 5, dj = n - di * 5;
      int hw = (pi + di) * WW + (pj + dj);
      float4 vx = *(const float4*)&y[((size_t)b * HW + hw) * DD + d4];
      *(float4*)&Xs[n][d4] = vx;
    }
    int k = idx >> 5;
    int d4 = (idx & 31) * 4;
    float4 vc = *(const float4*)&codewords[k * DD + d4];
    *(float4*)&cws[k][d4] = vc;
  }
  __syncthreads();

  // phase 2: build cwT, x2 per pixel, c2 per codeword, scale
  #pragma unroll
  for (int i = 0; i < 4; ++i) {
    int idx = t + 256 * i;
    int k = idx & 31;
    int d4 = (idx >> 5) * 4;          // 0..124
    float4 vc = *(const float4*)&cws[k][d4];
    cwT[d4 + 0][k] = vc.x; cwT[d4 + 1][k] = vc.y;
    cwT[d4 + 2][k] = vc.z; cwT[d4 + 3][k] = vc.w;
  }
  for (int n = wave; n < NPIX; n += 4) {
    float a = Xs[n][lane];
    float c = Xs[n][lane + 64];
    float r = a * a + c * c;
    #pragma unroll
    for (int off = 32; off; off >>= 1) r += __shfl_xor(r, off, 64);
    if (lane == 0) x2s[n] = r;
  }
  if (t < KK) {
    float s = 0.f;
    #pragma unroll 8
    for (int d4 = 0; d4 < DD; d4 += 4) {
      float4 c4 = *(const float4*)&cws[t][d4];
      s += c4.x * c4.x + c4.y * c4.y + c4.z * c4.z + c4.w * c4.w;
    }
    c2s[t] = s;
    scs[t] = scale[t];
  }
  __syncthreads();

  // phase 3+4 fused: dist + softmax. t -> (n = t>>3, 4 k's); 200 active.
  {
    const int n = t >> 3;             // 0..31, active n < 25
    const int k0 = (t & 7) * 4;
    if (n < NPIX) {
      float a0 = 0.f, a1 = 0.f, a2 = 0.f, a3 = 0.f;
      #pragma unroll 8
      for (int d4 = 0; d4 < DD; d4 += 4) {
        float4 xv = *(const float4*)&Xs[n][d4];
        float4 c0 = *(const float4*)&cwT[d4 + 0][k0];
        float4 c1 = *(const float4*)&cwT[d4 + 1][k0];
        float4 c2 = *(const float4*)&cwT[d4 + 2][k0];
        float4 c3 = *(const float4*)&cwT[d4 + 3][k0];
        a0 += xv.x * c0.x + xv.y * c1.x + xv.z * c2.x + xv.w * c3.x;
        a1 += xv.x * c0.y + xv.y * c1.y + xv.z * c2.y + xv.w * c3.y;
        a2 += xv.x * c0.z + xv.y * c1.z + xv.z * c2.z + xv.w * c3.z;
        a3 += xv.x * c0.w + xv.y * c1.w + xv.z * c2.w + xv.w * c3.w;
      }
      float x2 = x2s[n];
      float l0 = scs[k0 + 0] * (x2 - 2.f * a0 + c2s[k0 + 0]);
      float l1 = scs[k0 + 1] * (x2 - 2.f * a1 + c2s[k0 + 1]);
      float l2 = scs[k0 + 2] * (x2 - 2.f * a2 + c2s[k0 + 2]);
      float l3 = scs[k0 + 3] * (x2 - 2.f * a3 + c2s[k0 + 3]);
      float m = fmaxf(fmaxf(l0, l1), fmaxf(l2, l3));
      m = fmaxf(m, __shfl_xor(m, 1));
      m = fmaxf(m, __shfl_xor(m, 2));
      m = fmaxf(m, __shfl_xor(m, 4));
      float e0 = __expf(l0 - m), e1 = __expf(l1 - m);
      float e2 = __expf(l2 - m), e3 = __expf(l3 - m);
      float s = e0 + e1 + e2 + e3;
      s += __shfl_xor(s, 1);
      s += __shfl_xor(s, 2);
      s += __shfl_xor(s, 4);
      float inv = 1.f / s;
      *(float4*)&Am[n][k0] =
          make_float4(e0 * inv, e1 * inv, e2 * inv, e3 * inv);
    }
  }
  __syncthreads();

  // phase 5: column sums s[k] = sum_n A[n,k] (32 lanes, conflict-free)
  if (t < KK) {
    float s = 0.f;
    #pragma unroll
    for (int n = 0; n < NPIX; ++n) s += Am[n][t];
    sks[t] = s;
  }
  __syncthreads();

  // phase 6: E[k,d] = sum_n A*X - s[k]*cw[k,d]; thread = 8k x 2d tile
  const int dd = (t & 63) * 2;
  const int k0 = (t >> 6) * 8;      // wave-uniform
  float ea[8][2];
  #pragma unroll
  for (int kk = 0; kk < 8; ++kk) { ea[kk][0] = 0.f; ea[kk][1] = 0.f; }
  #pragma unroll 5
  for (int n = 0; n < NPIX; ++n) {
    float2 xv = *(const float2*)&Xs[n][dd];
    float4 q0 = *(const float4*)&Am[n][k0];
    float4 q1 = *(const float4*)&Am[n][k0 + 4];
    float av[8] = {q0.x, q0.y, q0.z, q0.w, q1.x, q1.y, q1.z, q1.w};
    #pragma unroll
    for (int kk = 0; kk < 8; ++kk) {
      ea[kk][0] += av[kk] * xv.x;
      ea[kk][1] += av[kk] * xv.y;
    }
  }
  float ss = 0.f;
  #pragma unroll
  for (int kk = 0; kk < 8; ++kk) {
    int k = k0 + kk;
    float s = sks[k];
    float2 cv = *(const float2*)&cws[k][dd];
    ea[kk][0] -= s * cv.x;
    ea[kk][1] -= s * cv.y;
    ss += ea[kk][0] * ea[kk][0] + ea[kk][1] * ea[kk][1];
  }
  #pragma unroll
  for (int off = 32; off; off >>= 1) ss += __shfl_xor(ss, off, 64);
  if (lane == 0) red[wave] = ss;
  __syncthreads();
  if (t == 0) {
    float tot = red[0] + red[1] + red[2] + red[3];
    red[4] = 1.f / fmaxf(sqrtf(tot), 1e-12f);
  }
  __syncthreads();
  float rn = red[4];
  float* vb = v + (size_t)b * KD;
  #pragma unroll
  for (int kk = 0; kk < 8; ++kk) {
    int k = k0 + kk;
    atomicAdd(&vb[k * DD + dd + 0], ea[kk][0] * rn);
    atomicAdd(&vb[k * DD + dd + 1], ea[kk][1] * rn);
  }
}

// ---------------------------------------------------------------------------
// Kernel 4: classifier out[32,1000] = v @ cls_w^T + cls_b. 2 classes/wave.
// ---------------------------------------------------------------------------
__global__ __launch_bounds__(256) void k_cls(const float* __restrict__ v,
    const float* __restrict__ cls_w, const float* __restrict__ cls_b,
    float* __restrict__ out) {
  const int wave = threadIdx.x >> 6;
  const int lane = threadIdx.x & 63;
  const int n0 = blockIdx.x * 8 + wave * 2;
  const float* w0 = cls_w + (size_t)n0 * KD;
  const float* w1 = cls_w + (size_t)(n0 + 1) * KD;
  float acc0[NB], acc1[NB];
  #pragma unroll
  for (int b = 0; b < NB; ++b) { acc0[b] = 0.f; acc1[b] = 0.f; }
  #pragma unroll 2
  for (int i = 0; i < 16; ++i) {
    int kd = i * 256 + lane * 4;
    float4 a4 = *(const float4*)&w0[kd];
    float4 b4 = *(const float4*)&w1[kd];
    #pragma unroll
    for (int b = 0; b < NB; ++b) {
      float4 v4 = *(const float4*)&v[b * KD + kd];
      acc0[b] += a4.x * v4.x + a4.y * v4.y + a4.z * v4.z + a4.w * v4.w;
      acc1[b] += b4.x * v4.x + b4.y * v4.y + b4.z * v4.z + b4.w * v4.w;
    }
  }
  #pragma unroll
  for (int b = 0; b < NB; ++b) {
    float r0 = acc0[b], r1 = acc1[b];
    #pragma unroll
    for (int off = 32; off; off >>= 1) {
      r0 += __shfl_xor(r0, off, 64);
      r1 += __shfl_xor(r1, off, 64);
    }
    if (lane == 0) {
      out[b * NCLASS + n0]     = r0 + cls_b[n0];
      out[b * NCLASS + n0 + 1] = r1 + cls_b[n0 + 1];
    }
  }
}

// ---------------------------------------------------------------------------
extern "C" void kernel_launch(void* const* d_in, const int* in_sizes, int n_in,
                              void* d_out, int out_size, void* d_ws, size_t ws_size,
                              hipStream_t stream) {
  const float* x         = (const float*)d_in[0];
  const float* conv_w    = (const float*)d_in[1];
  const float* conv_b    = (const float*)d_in[2];
  const float* bn_gamma  = (const float*)d_in[3];
  const float* bn_beta   = (const float*)d_in[4];
  const float* bn_mean   = (const float*)d_in[5];
  const float* bn_var    = (const float*)d_in[6];
  const float* codewords = (const float*)d_in[7];
  const float* scale     = (const float*)d_in[8];
  const float* cls_w     = (const float*)d_in[9];
  const float* cls_b     = (const float*)d_in[10];
  float* out = (float*)d_out;

  // ws layout: w_t (1MB) | y_part[nsplit] (3.2MB ea) | y (3.2MB) | v (0.5MB)
  // nsplit chosen from {4,2,1} by what fits ws_size (launch-invariant ->
  // same work every call, graph-capture safe).
  const size_t FIXED = ((size_t)CIN * DD + (size_t)YELEMS + (size_t)NB * KD)
                       * sizeof(float);
  int nsplit = 1;
  if (ws_size >= FIXED + 4 * (size_t)YELEMS * sizeof(float)) nsplit = 4;
  else if (ws_size >= FIXED + 2 * (size_t)YELEMS * sizeof(float)) nsplit = 2;
  const int cspl = CIN / nsplit;

  float* wt     = (float*)d_ws;
  float* y_part = wt + (size_t)CIN * DD;
  float* y      = y_part + (size_t)nsplit * YELEMS;
  float* v      = y + (size_t)YELEMS;

  hipMemsetAsync(v, 0, (size_t)NB * KD * sizeof(float), stream);

  k_wt<<<dim3(CIN / 32, DD / 32), 256, 0, stream>>>(conv_w, wt);
  k_conv<<<dim3(7, nsplit, NB), 256, 0, stream>>>(x, wt, y_part, cspl);
  k_bnred<<<YELEMS / (256 * 4), 256, 0, stream>>>(
      y_part, y, conv_b, bn_gamma, bn_beta, bn_mean, bn_var, nsplit);
  k_encode<<<NB * NP, 256, 0, stream>>>(y, codewords, scale, v);
  k_cls<<<NCLASS / 8, 256, 0, stream>>>(v, cls_w, cls_b, out);
}

// Round 7
// 333.757 us; speedup vs baseline: 1.4918x; 1.1745x over previous
//
#include <hip/hip_runtime.h>
#include <math.h>

#define NB 32
#define CIN 2048
#define HH 14
#define WW 14
#define HW 196
#define DD 128
#define KK 32
#define NCLASS 1000
#define PWN 10
#define NP 100
#define NPIX 25
#define KD 4096
#define BN_EPS 1e-5f
#define YELEMS (NB * HW * DD)    // 802816
#define MTOT (NB * HW)           // 6272 flattened pixels
#define MT 128                   // M-tile
#define KS 16                    // K-step channels

// ---------------------------------------------------------------------------
// Kernel 0: transpose conv_w [D][CIN] -> w_t [CIN][D] (one-time, ~1 MB).
// ---------------------------------------------------------------------------
__global__ __launch_bounds__(256) void k_wt(const float* __restrict__ cw,
                                            float* __restrict__ wt) {
  __shared__ float T[32][33];
  const int tx = threadIdx.x & 31;
  const int ty = threadIdx.x >> 5;          // 0..7
  const int c0 = blockIdx.x * 32;
  const int d0 = blockIdx.y * 32;
  #pragma unroll
  for (int k = 0; k < 4; ++k)
    T[ty + 8 * k][tx] = cw[(size_t)(d0 + ty + 8 * k) * CIN + c0 + tx];
  __syncthreads();
  #pragma unroll
  for (int k = 0; k < 4; ++k)
    wt[(size_t)(c0 + ty + 8 * k) * DD + d0 + tx] = T[tx][ty + 8 * k];
}

// ---------------------------------------------------------------------------
// Kernel 1: 1x1 conv as LDS-staged double-buffered fp32 GEMM.
// grid (49 m-tiles of 128, ksplit, 1), block 256 (4 waves).
// Tile 128m x 128d, K-step 16. Thread 8p x 8d in four 4x4 quadrants:
// x-reads broadcast (free), w-reads 2-way alias (free, m136).
// T14 order per K-step: issue next global loads -> compute (2048 VALU cyc
// covers ~900cyc HBM latency) -> ds_write to other buffer -> 1 barrier.
// ---------------------------------------------------------------------------
__global__ __launch_bounds__(256) void k_conv(const float* __restrict__ x,
                                              const float* __restrict__ wt,
                                              float* __restrict__ y_part,
                                              int cspl) {
  __shared__ float Xs[2][KS][132];   // pad 132: row bank shift 4
  __shared__ float Ws[2][KS][132];

  const int t = threadIdx.x;
  const int m0 = blockIdx.x * MT;
  const int s = blockIdx.y;
  const int c0 = s * cspl;
  const int nsteps = cspl / KS;

  // ---- staging geometry (fixed per thread): row sr of K-step, 8 m/d cols
  const int sr = t >> 4;              // 0..15  (c-row within K-step)
  const int sc = (t & 15) * 8;        // 0..120 (col start, mult of 8)
  // x cols are 8 consecutive m starting at m0+sc; split into two f4 chunks
  // that may straddle an image boundary (hw0==192 only; both chunks stay
  // f4-aligned since m and 196 are multiples of 4).
  const int msb = m0 + sc;
  const int b0i = msb / HW, h0 = msb - b0i * HW;
  const int m2 = msb + 4;
  const int b1i = m2 / HW, h1 = m2 - b1i * HW;
  const float* xp1 = x + (size_t)b0i * CIN * HW + (size_t)(c0 + sr) * HW + h0;
  const float* xp2 = x + (size_t)b1i * CIN * HW + (size_t)(c0 + sr) * HW + h1;
  const float* wp  = wt + (size_t)(c0 + sr) * DD + sc;

  // ---- compute geometry: pg = t>>4 (p-group), dg = t&15 (d-group)
  const int pg = t >> 4;
  const int dg = t & 15;
  const int pa = pg * 4;              // p quadrant offsets: pa, pa+64
  const int da = dg * 4;              // d quadrant offsets: da, da+64

  float4 acc[2][2][4];
  #pragma unroll
  for (int pi = 0; pi < 2; ++pi)
    #pragma unroll
    for (int di = 0; di < 2; ++di)
      #pragma unroll
      for (int i = 0; i < 4; ++i)
        acc[pi][di][i] = make_float4(0.f, 0.f, 0.f, 0.f);

  // prologue: stage step 0 into buf 0
  {
    float4 xv1 = *(const float4*)xp1;
    float4 xv2 = *(const float4*)xp2;
    float4 wv1 = *(const float4*)wp;
    float4 wv2 = *(const float4*)(wp + 4);
    *(float4*)&Xs[0][sr][sc]     = xv1;
    *(float4*)&Xs[0][sr][sc + 4] = xv2;
    *(float4*)&Ws[0][sr][sc]     = wv1;
    *(float4*)&Ws[0][sr][sc + 4] = wv2;
  }
  __syncthreads();

  for (int ks = 0; ks < nsteps; ++ks) {
    const int cur = ks & 1;
    float4 xv1, xv2, wv1, wv2;
    const bool more = (ks + 1 < nsteps);
    if (more) {                       // issue next-step global loads EARLY
      const size_t coff = (size_t)(ks + 1) * KS * HW;
      const size_t woff = (size_t)(ks + 1) * KS * DD;
      xv1 = *(const float4*)(xp1 + coff);
      xv2 = *(const float4*)(xp2 + coff);
      wv1 = *(const float4*)(wp + woff);
      wv2 = *(const float4*)(wp + woff + 4);
    }
    // compute on current buffer: 16c x 64 FMA/thread
    #pragma unroll
    for (int c = 0; c < KS; ++c) {
      float4 xa = *(const float4*)&Xs[cur][c][pa];
      float4 xb = *(const float4*)&Xs[cur][c][pa + 64];
      float4 wa = *(const float4*)&Ws[cur][c][da];
      float4 wb = *(const float4*)&Ws[cur][c][da + 64];
      float xs0[4] = {xa.x, xa.y, xa.z, xa.w};
      float xs1[4] = {xb.x, xb.y, xb.z, xb.w};
      #pragma unroll
      for (int i = 0; i < 4; ++i) {
        acc[0][0][i].x += xs0[i] * wa.x; acc[0][0][i].y += xs0[i] * wa.y;
        acc[0][0][i].z += xs0[i] * wa.z; acc[0][0][i].w += xs0[i] * wa.w;
        acc[0][1][i].x += xs0[i] * wb.x; acc[0][1][i].y += xs0[i] * wb.y;
        acc[0][1][i].z += xs0[i] * wb.z; acc[0][1][i].w += xs0[i] * wb.w;
        acc[1][0][i].x += xs1[i] * wa.x; acc[1][0][i].y += xs1[i] * wa.y;
        acc[1][0][i].z += xs1[i] * wa.z; acc[1][0][i].w += xs1[i] * wa.w;
        acc[1][1][i].x += xs1[i] * wb.x; acc[1][1][i].y += xs1[i] * wb.y;
        acc[1][1][i].z += xs1[i] * wb.z; acc[1][1][i].w += xs1[i] * wb.w;
      }
    }
    if (more) {                       // write next buffer (loads landed
      const int nxt = cur ^ 1;        // during the 2048-cyc compute)
      *(float4*)&Xs[nxt][sr][sc]     = xv1;
      *(float4*)&Xs[nxt][sr][sc + 4] = xv2;
      *(float4*)&Ws[nxt][sr][sc]     = wv1;
      *(float4*)&Ws[nxt][sr][sc + 4] = wv2;
    }
    __syncthreads();
  }

  // epilogue: y_part[s] is flat [m][d] (== [b][hw][d]); coalesced f4 stores
  float* yp = y_part + (size_t)s * YELEMS + (size_t)m0 * DD;
  #pragma unroll
  for (int pi = 0; pi < 2; ++pi)
    #pragma unroll
    for (int i = 0; i < 4; ++i) {
      const int row = pa + pi * 64 + i;
      #pragma unroll
      for (int di = 0; di < 2; ++di)
        *(float4*)(yp + (size_t)row * DD + da + di * 64) = acc[pi][di][i];
    }
}

// ---------------------------------------------------------------------------
// Kernel 2: reduce nsplit partials + conv bias + BN(eval) + ReLU -> y.
// ---------------------------------------------------------------------------
__global__ __launch_bounds__(256) void k_bnred(const float* __restrict__ y_part,
    float* __restrict__ y, const float* __restrict__ convb,
    const float* __restrict__ gamma, const float* __restrict__ beta,
    const float* __restrict__ mean, const float* __restrict__ var,
    int nsplit) {
  int idx = blockIdx.x * 256 + threadIdx.x;   // float4 index, exact grid
  float4 a = *(const float4*)&y_part[(size_t)idx * 4];
  for (int s = 1; s < nsplit; ++s) {
    float4 p = *(const float4*)&y_part[(size_t)s * YELEMS + (size_t)idx * 4];
    a.x += p.x; a.y += p.y; a.z += p.z; a.w += p.w;
  }
  int d4 = (idx * 4) & (DD - 1);
  float o[4] = {a.x, a.y, a.z, a.w};
  #pragma unroll
  for (int j = 0; j < 4; ++j) {
    int d = d4 + j;
    float inv = gamma[d] * rsqrtf(var[d] + BN_EPS);
    float val = (o[j] + convb[d] - mean[d]) * inv + beta[d];
    o[j] = fmaxf(val, 0.f);
  }
  *(float4*)&y[(size_t)idx * 4] = make_float4(o[0], o[1], o[2], o[3]);
}

// ---------------------------------------------------------------------------
// Kernel 3: soft-VQ encode per (b, patch). Block 256, grid 3200. (unchanged)
// ---------------------------------------------------------------------------
__global__ __launch_bounds__(256) void k_encode(const float* __restrict__ y,
    const float* __restrict__ codewords, const float* __restrict__ scale,
    float* __restrict__ v) {
  __shared__ float Xs[NPIX][132];
  __shared__ float cws[KK][132];
  __shared__ float cwT[DD][36];
  __shared__ float Am[NPIX][36];
  __shared__ float x2s[NPIX];
  __shared__ float sks[KK];
  __shared__ float c2s[KK];
  __shared__ float scs[KK];
  __shared__ float red[5];

  const int t = threadIdx.x;
  const int bp = blockIdx.x;
  const int b = bp / NP;
  const int p = bp - b * NP;
  const int pi = p / PWN, pj = p - pi * PWN;
  const int wave = t >> 6, lane = t & 63;

  #pragma unroll
  for (int i = 0; i < 4; ++i) {
    int idx = t + 256 * i;
    if (idx < NPIX * 32) {
      int n = idx >> 5;
      int d4 = (idx & 31) * 4;
      int di = n / 5, dj = n - di * 5;
      int hw = (pi + di) * WW + (pj + dj);
      float4 vx = *(const float4*)&y[((size_t)b * HW + hw) * DD + d4];
      *(float4*)&Xs[n][d4] = vx;
    }
    int k = idx >> 5;
    int d4 = (idx & 31) * 4;
    float4 vc = *(const float4*)&codewords[k * DD + d4];
    *(float4*)&cws[k][d4] = vc;
  }
  __syncthreads();

  #pragma unroll
  for (int i = 0; i < 4; ++i) {
    int idx = t + 256 * i;
    int k = idx & 31;
    int d4 = (idx >> 5) * 4;
    float4 vc = *(const float4*)&cws[k][d4];
    cwT[d4 + 0][k] = vc.x; cwT[d4 + 1][k] = vc.y;
    cwT[d4 + 2][k] = vc.z; cwT[d4 + 3][k] = vc.w;
  }
  for (int n = wave; n < NPIX; n += 4) {
    float a = Xs[n][lane];
    float c = Xs[n][lane + 64];
    float r = a * a + c * c;
    #pragma unroll
    for (int off = 32; off; off >>= 1) r += __shfl_xor(r, off, 64);
    if (lane == 0) x2s[n] = r;
  }
  if (t < KK) {
    float s = 0.f;
    #pragma unroll 8
    for (int d4 = 0; d4 < DD; d4 += 4) {
      float4 c4 = *(const float4*)&cws[t][d4];
      s += c4.x * c4.x + c4.y * c4.y + c4.z * c4.z + c4.w * c4.w;
    }
    c2s[t] = s;
    scs[t] = scale[t];
  }
  __syncthreads();

  {
    const int n = t >> 3;
    const int k0 = (t & 7) * 4;
    if (n < NPIX) {
      float a0 = 0.f, a1 = 0.f, a2 = 0.f, a3 = 0.f;
      #pragma unroll 8
      for (int d4 = 0; d4 < DD; d4 += 4) {
        float4 xv = *(const float4*)&Xs[n][d4];
        float4 c0 = *(const float4*)&cwT[d4 + 0][k0];
        float4 c1 = *(const float4*)&cwT[d4 + 1][k0];
        float4 c2 = *(const float4*)&cwT[d4 + 2][k0];
        float4 c3 = *(const float4*)&cwT[d4 + 3][k0];
        a0 += xv.x * c0.x + xv.y * c1.x + xv.z * c2.x + xv.w * c3.x;
        a1 += xv.x * c0.y + xv.y * c1.y + xv.z * c2.y + xv.w * c3.y;
        a2 += xv.x * c0.z + xv.y * c1.z + xv.z * c2.z + xv.w * c3.z;
        a3 += xv.x * c0.w + xv.y * c1.w + xv.z * c2.w + xv.w * c3.w;
      }
      float x2 = x2s[n];
      float l0 = scs[k0 + 0] * (x2 - 2.f * a0 + c2s[k0 + 0]);
      float l1 = scs[k0 + 1] * (x2 - 2.f * a1 + c2s[k0 + 1]);
      float l2 = scs[k0 + 2] * (x2 - 2.f * a2 + c2s[k0 + 2]);
      float l3 = scs[k0 + 3] * (x2 - 2.f * a3 + c2s[k0 + 3]);
      float m = fmaxf(fmaxf(l0, l1), fmaxf(l2, l3));
      m = fmaxf(m, __shfl_xor(m, 1));
      m = fmaxf(m, __shfl_xor(m, 2));
      m = fmaxf(m, __shfl_xor(m, 4));
      float e0 = __expf(l0 - m), e1 = __expf(l1 - m);
      float e2 = __expf(l2 - m), e3 = __expf(l3 - m);
      float s = e0 + e1 + e2 + e3;
      s += __shfl_xor(s, 1);
      s += __shfl_xor(s, 2);
      s += __shfl_xor(s, 4);
      float inv = 1.f / s;
      *(float4*)&Am[n][k0] =
          make_float4(e0 * inv, e1 * inv, e2 * inv, e3 * inv);
    }
  }
  __syncthreads();

  if (t < KK) {
    float s = 0.f;
    #pragma unroll
    for (int n = 0; n < NPIX; ++n) s += Am[n][t];
    sks[t] = s;
  }
  __syncthreads();

  const int dd = (t & 63) * 2;
  const int k0 = (t >> 6) * 8;
  float ea[8][2];
  #pragma unroll
  for (int kk = 0; kk < 8; ++kk) { ea[kk][0] = 0.f; ea[kk][1] = 0.f; }
  #pragma unroll 5
  for (int n = 0; n < NPIX; ++n) {
    float2 xv = *(const float2*)&Xs[n][dd];
    float4 q0 = *(const float4*)&Am[n][k0];
    float4 q1 = *(const float4*)&Am[n][k0 + 4];
    float av[8] = {q0.x, q0.y, q0.z, q0.w, q1.x, q1.y, q1.z, q1.w};
    #pragma unroll
    for (int kk = 0; kk < 8; ++kk) {
      ea[kk][0] += av[kk] * xv.x;
      ea[kk][1] += av[kk] * xv.y;
    }
  }
  float ss = 0.f;
  #pragma unroll
  for (int kk = 0; kk < 8; ++kk) {
    int k = k0 + kk;
    float s = sks[k];
    float2 cv = *(const float2*)&cws[k][dd];
    ea[kk][0] -= s * cv.x;
    ea[kk][1] -= s * cv.y;
    ss += ea[kk][0] * ea[kk][0] + ea[kk][1] * ea[kk][1];
  }
  #pragma unroll
  for (int off = 32; off; off >>= 1) ss += __shfl_xor(ss, off, 64);
  if (lane == 0) red[wave] = ss;
  __syncthreads();
  if (t == 0) {
    float tot = red[0] + red[1] + red[2] + red[3];
    red[4] = 1.f / fmaxf(sqrtf(tot), 1e-12f);
  }
  __syncthreads();
  float rn = red[4];
  float* vb = v + (size_t)b * KD;
  #pragma unroll
  for (int kk = 0; kk < 8; ++kk) {
    int k = k0 + kk;
    atomicAdd(&vb[k * DD + dd + 0], ea[kk][0] * rn);
    atomicAdd(&vb[k * DD + dd + 1], ea[kk][1] * rn);
  }
}

// ---------------------------------------------------------------------------
// Kernel 4: classifier out[32,1000] = v @ cls_w^T + cls_b. (unchanged)
// ---------------------------------------------------------------------------
__global__ __launch_bounds__(256) void k_cls(const float* __restrict__ v,
    const float* __restrict__ cls_w, const float* __restrict__ cls_b,
    float* __restrict__ out) {
  const int wave = threadIdx.x >> 6;
  const int lane = threadIdx.x & 63;
  const int n0 = blockIdx.x * 8 + wave * 2;
  const float* w0 = cls_w + (size_t)n0 * KD;
  const float* w1 = cls_w + (size_t)(n0 + 1) * KD;
  float acc0[NB], acc1[NB];
  #pragma unroll
  for (int b = 0; b < NB; ++b) { acc0[b] = 0.f; acc1[b] = 0.f; }
  #pragma unroll 2
  for (int i = 0; i < 16; ++i) {
    int kd = i * 256 + lane * 4;
    float4 a4 = *(const float4*)&w0[kd];
    float4 b4 = *(const float4*)&w1[kd];
    #pragma unroll
    for (int b = 0; b < NB; ++b) {
      float4 v4 = *(const float4*)&v[b * KD + kd];
      acc0[b] += a4.x * v4.x + a4.y * v4.y + a4.z * v4.z + a4.w * v4.w;
      acc1[b] += b4.x * v4.x + b4.y * v4.y + b4.z * v4.z + b4.w * v4.w;
    }
  }
  #pragma unroll
  for (int b = 0; b < NB; ++b) {
    float r0 = acc0[b], r1 = acc1[b];
    #pragma unroll
    for (int off = 32; off; off >>= 1) {
      r0 += __shfl_xor(r0, off, 64);
      r1 += __shfl_xor(r1, off, 64);
    }
    if (lane == 0) {
      out[b * NCLASS + n0]     = r0 + cls_b[n0];
      out[b * NCLASS + n0 + 1] = r1 + cls_b[n0 + 1];
    }
  }
}

// ---------------------------------------------------------------------------
extern "C" void kernel_launch(void* const* d_in, const int* in_sizes, int n_in,
                              void* d_out, int out_size, void* d_ws, size_t ws_size,
                              hipStream_t stream) {
  const float* x         = (const float*)d_in[0];
  const float* conv_w    = (const float*)d_in[1];
  const float* conv_b    = (const float*)d_in[2];
  const float* bn_gamma  = (const float*)d_in[3];
  const float* bn_beta   = (const float*)d_in[4];
  const float* bn_mean   = (const float*)d_in[5];
  const float* bn_var    = (const float*)d_in[6];
  const float* codewords = (const float*)d_in[7];
  const float* scale     = (const float*)d_in[8];
  const float* cls_w     = (const float*)d_in[9];
  const float* cls_b     = (const float*)d_in[10];
  float* out = (float*)d_out;

  // ws layout: w_t (1MB) | y_part[ksplit] (3.2MB ea) | y (3.2MB) | v (0.5MB)
  // ksplit from {16,8,4,2} by what fits ws_size (launch-invariant).
  const size_t FIXED = ((size_t)CIN * DD + (size_t)YELEMS + (size_t)NB * KD)
                       * sizeof(float);
  int ksplit = 2;
  if (ws_size >= FIXED + 16 * (size_t)YELEMS * sizeof(float)) ksplit = 16;
  else if (ws_size >= FIXED + 8 * (size_t)YELEMS * sizeof(float)) ksplit = 8;
  else if (ws_size >= FIXED + 4 * (size_t)YELEMS * sizeof(float)) ksplit = 4;
  const int cspl = CIN / ksplit;

  float* wt     = (float*)d_ws;
  float* y_part = wt + (size_t)CIN * DD;
  float* y      = y_part + (size_t)ksplit * YELEMS;
  float* v      = y + (size_t)YELEMS;

  hipMemsetAsync(v, 0, (size_t)NB * KD * sizeof(float), stream);

  k_wt<<<dim3(CIN / 32, DD / 32), 256, 0, stream>>>(conv_w, wt);
  k_conv<<<dim3(MTOT / MT, ksplit), 256, 0, stream>>>(x, wt, y_part, cspl);
  k_bnred<<<YELEMS / (256 * 4), 256, 0, stream>>>(
      y_part, y, conv_b, bn_gamma, bn_beta, bn_mean, bn_var, ksplit);
  k_encode<<<NB * NP, 256, 0, stream>>>(y, codewords, scale, v);
  k_cls<<<NCLASS / 8, 256, 0, stream>>>(v, cls_w, cls_b, out);
}

// Round 8
// 295.796 us; speedup vs baseline: 1.6832x; 1.1283x over previous
//
#include <hip/hip_runtime.h>
#include <math.h>

#define NB 32
#define CIN 2048
#define HH 14
#define WW 14
#define HW 196
#define DD 128
#define KK 32
#define NCLASS 1000
#define PWN 10
#define NP 100
#define NPIX 25
#define KD 4096
#define BN_EPS 1e-5f
#define YELEMS (NB * HW * DD)    // 802816
#define MTOT (NB * HW)           // 6272 flattened pixels
#define MT 128                   // M-tile
#define KS 16                    // K-step channels

// ---------------------------------------------------------------------------
// Kernel 0: transpose conv_w [D][CIN] -> w_t [CIN][D] (one-time, ~1 MB).
// ---------------------------------------------------------------------------
__global__ __launch_bounds__(256) void k_wt(const float* __restrict__ cw,
                                            float* __restrict__ wt) {
  __shared__ float T[32][33];
  const int tx = threadIdx.x & 31;
  const int ty = threadIdx.x >> 5;
  const int c0 = blockIdx.x * 32;
  const int d0 = blockIdx.y * 32;
  #pragma unroll
  for (int k = 0; k < 4; ++k)
    T[ty + 8 * k][tx] = cw[(size_t)(d0 + ty + 8 * k) * CIN + c0 + tx];
  __syncthreads();
  #pragma unroll
  for (int k = 0; k < 4; ++k)
    wt[(size_t)(c0 + ty + 8 * k) * DD + d0 + tx] = T[tx][ty + 8 * k];
}

// ---------------------------------------------------------------------------
// Kernel 1: 1x1 conv as LDS-staged double-buffered fp32 GEMM. (unchanged)
// ---------------------------------------------------------------------------
__global__ __launch_bounds__(256) void k_conv(const float* __restrict__ x,
                                              const float* __restrict__ wt,
                                              float* __restrict__ y_part,
                                              int cspl) {
  __shared__ float Xs[2][KS][132];
  __shared__ float Ws[2][KS][132];

  const int t = threadIdx.x;
  const int m0 = blockIdx.x * MT;
  const int s = blockIdx.y;
  const int c0 = s * cspl;
  const int nsteps = cspl / KS;

  const int sr = t >> 4;
  const int sc = (t & 15) * 8;
  const int msb = m0 + sc;
  const int b0i = msb / HW, h0 = msb - b0i * HW;
  const int m2 = msb + 4;
  const int b1i = m2 / HW, h1 = m2 - b1i * HW;
  const float* xp1 = x + (size_t)b0i * CIN * HW + (size_t)(c0 + sr) * HW + h0;
  const float* xp2 = x + (size_t)b1i * CIN * HW + (size_t)(c0 + sr) * HW + h1;
  const float* wp  = wt + (size_t)(c0 + sr) * DD + sc;

  const int pg = t >> 4;
  const int dg = t & 15;
  const int pa = pg * 4;
  const int da = dg * 4;

  float4 acc[2][2][4];
  #pragma unroll
  for (int pi = 0; pi < 2; ++pi)
    #pragma unroll
    for (int di = 0; di < 2; ++di)
      #pragma unroll
      for (int i = 0; i < 4; ++i)
        acc[pi][di][i] = make_float4(0.f, 0.f, 0.f, 0.f);

  {
    float4 xv1 = *(const float4*)xp1;
    float4 xv2 = *(const float4*)xp2;
    float4 wv1 = *(const float4*)wp;
    float4 wv2 = *(const float4*)(wp + 4);
    *(float4*)&Xs[0][sr][sc]     = xv1;
    *(float4*)&Xs[0][sr][sc + 4] = xv2;
    *(float4*)&Ws[0][sr][sc]     = wv1;
    *(float4*)&Ws[0][sr][sc + 4] = wv2;
  }
  __syncthreads();

  for (int ks = 0; ks < nsteps; ++ks) {
    const int cur = ks & 1;
    float4 xv1, xv2, wv1, wv2;
    const bool more = (ks + 1 < nsteps);
    if (more) {
      const size_t coff = (size_t)(ks + 1) * KS * HW;
      const size_t woff = (size_t)(ks + 1) * KS * DD;
      xv1 = *(const float4*)(xp1 + coff);
      xv2 = *(const float4*)(xp2 + coff);
      wv1 = *(const float4*)(wp + woff);
      wv2 = *(const float4*)(wp + woff + 4);
    }
    #pragma unroll
    for (int c = 0; c < KS; ++c) {
      float4 xa = *(const float4*)&Xs[cur][c][pa];
      float4 xb = *(const float4*)&Xs[cur][c][pa + 64];
      float4 wa = *(const float4*)&Ws[cur][c][da];
      float4 wb = *(const float4*)&Ws[cur][c][da + 64];
      float xs0[4] = {xa.x, xa.y, xa.z, xa.w};
      float xs1[4] = {xb.x, xb.y, xb.z, xb.w};
      #pragma unroll
      for (int i = 0; i < 4; ++i) {
        acc[0][0][i].x += xs0[i] * wa.x; acc[0][0][i].y += xs0[i] * wa.y;
        acc[0][0][i].z += xs0[i] * wa.z; acc[0][0][i].w += xs0[i] * wa.w;
        acc[0][1][i].x += xs0[i] * wb.x; acc[0][1][i].y += xs0[i] * wb.y;
        acc[0][1][i].z += xs0[i] * wb.z; acc[0][1][i].w += xs0[i] * wb.w;
        acc[1][0][i].x += xs1[i] * wa.x; acc[1][0][i].y += xs1[i] * wa.y;
        acc[1][0][i].z += xs1[i] * wa.z; acc[1][0][i].w += xs1[i] * wa.w;
        acc[1][1][i].x += xs1[i] * wb.x; acc[1][1][i].y += xs1[i] * wb.y;
        acc[1][1][i].z += xs1[i] * wb.z; acc[1][1][i].w += xs1[i] * wb.w;
      }
    }
    if (more) {
      const int nxt = cur ^ 1;
      *(float4*)&Xs[nxt][sr][sc]     = xv1;
      *(float4*)&Xs[nxt][sr][sc + 4] = xv2;
      *(float4*)&Ws[nxt][sr][sc]     = wv1;
      *(float4*)&Ws[nxt][sr][sc + 4] = wv2;
    }
    __syncthreads();
  }

  float* yp = y_part + (size_t)s * YELEMS + (size_t)m0 * DD;
  #pragma unroll
  for (int pi = 0; pi < 2; ++pi)
    #pragma unroll
    for (int i = 0; i < 4; ++i) {
      const int row = pa + pi * 64 + i;
      #pragma unroll
      for (int di = 0; di < 2; ++di)
        *(float4*)(yp + (size_t)row * DD + da + di * 64) = acc[pi][di][i];
    }
}

// ---------------------------------------------------------------------------
// Kernel 2: reduce ksplit partials + conv bias + BN(eval) + ReLU -> y.
// ---------------------------------------------------------------------------
__global__ __launch_bounds__(256) void k_bnred(const float* __restrict__ y_part,
    float* __restrict__ y, const float* __restrict__ convb,
    const float* __restrict__ gamma, const float* __restrict__ beta,
    const float* __restrict__ mean, const float* __restrict__ var,
    int nsplit) {
  int idx = blockIdx.x * 256 + threadIdx.x;
  float4 a = *(const float4*)&y_part[(size_t)idx * 4];
  for (int s = 1; s < nsplit; ++s) {
    float4 p = *(const float4*)&y_part[(size_t)s * YELEMS + (size_t)idx * 4];
    a.x += p.x; a.y += p.y; a.z += p.z; a.w += p.w;
  }
  int d4 = (idx * 4) & (DD - 1);
  float o[4] = {a.x, a.y, a.z, a.w};
  #pragma unroll
  for (int j = 0; j < 4; ++j) {
    int d = d4 + j;
    float inv = gamma[d] * rsqrtf(var[d] + BN_EPS);
    float val = (o[j] + convb[d] - mean[d]) * inv + beta[d];
    o[j] = fmaxf(val, 0.f);
  }
  *(float4*)&y[(size_t)idx * 4] = make_float4(o[0], o[1], o[2], o[3]);
}

// ---------------------------------------------------------------------------
// Kernel 3: soft-VQ encode. Grid (npart, NB); each block processes ppb
// patches serially, accumulates normalized contributions in registers, and
// writes ONE plain-store partial (no global atomics -> no RMW write churn).
// ---------------------------------------------------------------------------
__global__ __launch_bounds__(256) void k_encode(const float* __restrict__ y,
    const float* __restrict__ codewords, const float* __restrict__ scale,
    float* __restrict__ vpart, int ppb) {
  __shared__ float Xs[NPIX][132];
  __shared__ float cws[KK][132];
  __shared__ float cwT[DD][36];
  __shared__ float Am[NPIX][36];
  __shared__ float x2s[NPIX];
  __shared__ float sks[KK];
  __shared__ float c2s[KK];
  __shared__ float scs[KK];
  __shared__ float red[5];

  const int t = threadIdx.x;
  const int part = blockIdx.x;
  const int b = blockIdx.y;
  const int wave = t >> 6, lane = t & 63;

  // stage codewords once per block
  #pragma unroll
  for (int i = 0; i < 4; ++i) {
    int idx = t + 256 * i;
    int k = idx >> 5;
    int d4 = (idx & 31) * 4;
    *(float4*)&cws[k][d4] = *(const float4*)&codewords[k * DD + d4];
  }
  __syncthreads();
  #pragma unroll
  for (int i = 0; i < 4; ++i) {
    int idx = t + 256 * i;
    int k = idx & 31;
    int d4 = (idx >> 5) * 4;
    float4 vc = *(const float4*)&cws[k][d4];
    cwT[d4 + 0][k] = vc.x; cwT[d4 + 1][k] = vc.y;
    cwT[d4 + 2][k] = vc.z; cwT[d4 + 3][k] = vc.w;
  }
  if (t < KK) {
    float s = 0.f;
    #pragma unroll 8
    for (int d4 = 0; d4 < DD; d4 += 4) {
      float4 c4 = *(const float4*)&cws[t][d4];
      s += c4.x * c4.x + c4.y * c4.y + c4.z * c4.z + c4.w * c4.w;
    }
    c2s[t] = s;
    scs[t] = scale[t];
  }
  // visibility of cwT/c2s/scs guaranteed by the barriers inside the loop

  const int dd = (t & 63) * 2;
  const int k06 = (t >> 6) * 8;       // wave-uniform phase-6 k base
  float vacc[8][2];
  #pragma unroll
  for (int kk = 0; kk < 8; ++kk) { vacc[kk][0] = 0.f; vacc[kk][1] = 0.f; }

  for (int pp = 0; pp < ppb; ++pp) {
    const int p = part * ppb + pp;
    if (p >= NP) break;                // uniform across block
    const int pi = p / PWN, pj = p - pi * PWN;

    __syncthreads();                   // protect Xs/Am/red reuse
    // stage patch X (25x128)
    #pragma unroll
    for (int i = 0; i < 4; ++i) {
      int idx = t + 256 * i;
      if (idx < NPIX * 32) {
        int n = idx >> 5;
        int d4 = (idx & 31) * 4;
        int di = n / 5, dj = n - di * 5;
        int hw = (pi + di) * WW + (pj + dj);
        *(float4*)&Xs[n][d4] =
            *(const float4*)&y[((size_t)b * HW + hw) * DD + d4];
      }
    }
    __syncthreads();

    // x2 per pixel
    for (int n = wave; n < NPIX; n += 4) {
      float a = Xs[n][lane];
      float c = Xs[n][lane + 64];
      float r = a * a + c * c;
      #pragma unroll
      for (int off = 32; off; off >>= 1) r += __shfl_xor(r, off, 64);
      if (lane == 0) x2s[n] = r;
    }
    __syncthreads();

    // dist + softmax (200 active lanes; width-8 shuffle softmax)
    {
      const int n = t >> 3;
      const int k0 = (t & 7) * 4;
      if (n < NPIX) {
        float a0 = 0.f, a1 = 0.f, a2 = 0.f, a3 = 0.f;
        #pragma unroll 8
        for (int d4 = 0; d4 < DD; d4 += 4) {
          float4 xv = *(const float4*)&Xs[n][d4];
          float4 c0 = *(const float4*)&cwT[d4 + 0][k0];
          float4 c1 = *(const float4*)&cwT[d4 + 1][k0];
          float4 c2 = *(const float4*)&cwT[d4 + 2][k0];
          float4 c3 = *(const float4*)&cwT[d4 + 3][k0];
          a0 += xv.x * c0.x + xv.y * c1.x + xv.z * c2.x + xv.w * c3.x;
          a1 += xv.x * c0.y + xv.y * c1.y + xv.z * c2.y + xv.w * c3.y;
          a2 += xv.x * c0.z + xv.y * c1.z + xv.z * c2.z + xv.w * c3.z;
          a3 += xv.x * c0.w + xv.y * c1.w + xv.z * c2.w + xv.w * c3.w;
        }
        float x2 = x2s[n];
        float l0 = scs[k0 + 0] * (x2 - 2.f * a0 + c2s[k0 + 0]);
        float l1 = scs[k0 + 1] * (x2 - 2.f * a1 + c2s[k0 + 1]);
        float l2 = scs[k0 + 2] * (x2 - 2.f * a2 + c2s[k0 + 2]);
        float l3 = scs[k0 + 3] * (x2 - 2.f * a3 + c2s[k0 + 3]);
        float m = fmaxf(fmaxf(l0, l1), fmaxf(l2, l3));
        m = fmaxf(m, __shfl_xor(m, 1));
        m = fmaxf(m, __shfl_xor(m, 2));
        m = fmaxf(m, __shfl_xor(m, 4));
        float e0 = __expf(l0 - m), e1 = __expf(l1 - m);
        float e2 = __expf(l2 - m), e3 = __expf(l3 - m);
        float s = e0 + e1 + e2 + e3;
        s += __shfl_xor(s, 1);
        s += __shfl_xor(s, 2);
        s += __shfl_xor(s, 4);
        float inv = 1.f / s;
        *(float4*)&Am[n][k0] =
            make_float4(e0 * inv, e1 * inv, e2 * inv, e3 * inv);
      }
    }
    __syncthreads();

    // column sums
    if (t < KK) {
      float s = 0.f;
      #pragma unroll
      for (int n = 0; n < NPIX; ++n) s += Am[n][t];
      sks[t] = s;
    }
    __syncthreads();

    // E + L2 norm, accumulate into vacc
    float ea[8][2];
    #pragma unroll
    for (int kk = 0; kk < 8; ++kk) { ea[kk][0] = 0.f; ea[kk][1] = 0.f; }
    #pragma unroll 5
    for (int n = 0; n < NPIX; ++n) {
      float2 xv = *(const float2*)&Xs[n][dd];
      float4 q0 = *(const float4*)&Am[n][k06];
      float4 q1 = *(const float4*)&Am[n][k06 + 4];
      float av[8] = {q0.x, q0.y, q0.z, q0.w, q1.x, q1.y, q1.z, q1.w};
      #pragma unroll
      for (int kk = 0; kk < 8; ++kk) {
        ea[kk][0] += av[kk] * xv.x;
        ea[kk][1] += av[kk] * xv.y;
      }
    }
    float ss = 0.f;
    #pragma unroll
    for (int kk = 0; kk < 8; ++kk) {
      int k = k06 + kk;
      float s = sks[k];
      float2 cv = *(const float2*)&cws[k][dd];
      ea[kk][0] -= s * cv.x;
      ea[kk][1] -= s * cv.y;
      ss += ea[kk][0] * ea[kk][0] + ea[kk][1] * ea[kk][1];
    }
    #pragma unroll
    for (int off = 32; off; off >>= 1) ss += __shfl_xor(ss, off, 64);
    if (lane == 0) red[wave] = ss;
    __syncthreads();
    if (t == 0) {
      float tot = red[0] + red[1] + red[2] + red[3];
      red[4] = 1.f / fmaxf(sqrtf(tot), 1e-12f);
    }
    __syncthreads();
    float rn = red[4];
    #pragma unroll
    for (int kk = 0; kk < 8; ++kk) {
      vacc[kk][0] += ea[kk][0] * rn;
      vacc[kk][1] += ea[kk][1] * rn;
    }
  }

  // one coalesced plain-store partial per block
  float* vp = vpart + ((size_t)part * NB + b) * KD;
  #pragma unroll
  for (int kk = 0; kk < 8; ++kk)
    *(float2*)&vp[(k06 + kk) * DD + dd] =
        make_float2(vacc[kk][0], vacc[kk][1]);
}

// ---------------------------------------------------------------------------
// Kernel 3b: v[b][kd] = sum_part vpart[part][b][kd].
// ---------------------------------------------------------------------------
__global__ __launch_bounds__(256) void k_vred(const float* __restrict__ vpart,
                                              float* __restrict__ v,
                                              int npart) {
  int idx = blockIdx.x * 256 + threadIdx.x;   // f4 index over NB*KD/4
  float4 a = make_float4(0.f, 0.f, 0.f, 0.f);
  for (int pt = 0; pt < npart; ++pt) {
    float4 p = *(const float4*)&vpart[(size_t)pt * NB * KD + (size_t)idx * 4];
    a.x += p.x; a.y += p.y; a.z += p.z; a.w += p.w;
  }
  *(float4*)&v[(size_t)idx * 4] = a;
}

// ---------------------------------------------------------------------------
// Kernel 4: classifier out[32,1000] = v @ cls_w^T + cls_b. (unchanged)
// ---------------------------------------------------------------------------
__global__ __launch_bounds__(256) void k_cls(const float* __restrict__ v,
    const float* __restrict__ cls_w, const float* __restrict__ cls_b,
    float* __restrict__ out) {
  const int wave = threadIdx.x >> 6;
  const int lane = threadIdx.x & 63;
  const int n0 = blockIdx.x * 8 + wave * 2;
  const float* w0 = cls_w + (size_t)n0 * KD;
  const float* w1 = cls_w + (size_t)(n0 + 1) * KD;
  float acc0[NB], acc1[NB];
  #pragma unroll
  for (int b = 0; b < NB; ++b) { acc0[b] = 0.f; acc1[b] = 0.f; }
  #pragma unroll 2
  for (int i = 0; i < 16; ++i) {
    int kd = i * 256 + lane * 4;
    float4 a4 = *(const float4*)&w0[kd];
    float4 b4 = *(const float4*)&w1[kd];
    #pragma unroll
    for (int b = 0; b < NB; ++b) {
      float4 v4 = *(const float4*)&v[b * KD + kd];
      acc0[b] += a4.x * v4.x + a4.y * v4.y + a4.z * v4.z + a4.w * v4.w;
      acc1[b] += b4.x * v4.x + b4.y * v4.y + b4.z * v4.z + b4.w * v4.w;
    }
  }
  #pragma unroll
  for (int b = 0; b < NB; ++b) {
    float r0 = acc0[b], r1 = acc1[b];
    #pragma unroll
    for (int off = 32; off; off >>= 1) {
      r0 += __shfl_xor(r0, off, 64);
      r1 += __shfl_xor(r1, off, 64);
    }
    if (lane == 0) {
      out[b * NCLASS + n0]     = r0 + cls_b[n0];
      out[b * NCLASS + n0 + 1] = r1 + cls_b[n0 + 1];
    }
  }
}

// ---------------------------------------------------------------------------
extern "C" void kernel_launch(void* const* d_in, const int* in_sizes, int n_in,
                              void* d_out, int out_size, void* d_ws, size_t ws_size,
                              hipStream_t stream) {
  const float* x         = (const float*)d_in[0];
  const float* conv_w    = (const float*)d_in[1];
  const float* conv_b    = (const float*)d_in[2];
  const float* bn_gamma  = (const float*)d_in[3];
  const float* bn_beta   = (const float*)d_in[4];
  const float* bn_mean   = (const float*)d_in[5];
  const float* bn_var    = (const float*)d_in[6];
  const float* codewords = (const float*)d_in[7];
  const float* scale     = (const float*)d_in[8];
  const float* cls_w     = (const float*)d_in[9];
  const float* cls_b     = (const float*)d_in[10];
  float* out = (float*)d_out;

  // ws layout: w_t | scratch (y_part, later aliased by vpart) | y | v.
  // ksplit/npart chosen by ws_size (launch-invariant -> graph-safe).
  auto need = [](int kspl, int npart) -> size_t {
    size_t scratch = (size_t)kspl * YELEMS;
    size_t vp = (size_t)npart * NB * KD;
    if (vp > scratch) scratch = vp;
    return ((size_t)CIN * DD + scratch + (size_t)YELEMS
            + (size_t)NB * KD) * sizeof(float);
  };
  int ksplit, npart;
  if      (ws_size >= need(16, 25)) { ksplit = 16; npart = 25; }
  else if (ws_size >= need(8, 25))  { ksplit = 8;  npart = 25; }
  else if (ws_size >= need(4, 25))  { ksplit = 4;  npart = 25; }
  else                              { ksplit = 2;  npart = 10; }
  const int cspl = CIN / ksplit;
  const int ppb = (NP + npart - 1) / npart;
  size_t scratchf = (size_t)ksplit * YELEMS;
  if ((size_t)npart * NB * KD > scratchf) scratchf = (size_t)npart * NB * KD;

  float* wt      = (float*)d_ws;
  float* scratch = wt + (size_t)CIN * DD;     // y_part, then vpart
  float* y       = scratch + scratchf;
  float* v       = y + (size_t)YELEMS;

  k_wt<<<dim3(CIN / 32, DD / 32), 256, 0, stream>>>(conv_w, wt);
  k_conv<<<dim3(MTOT / MT, ksplit), 256, 0, stream>>>(x, wt, scratch, cspl);
  k_bnred<<<YELEMS / (256 * 4), 256, 0, stream>>>(
      scratch, y, conv_b, bn_gamma, bn_beta, bn_mean, bn_var, ksplit);
  k_encode<<<dim3(npart, NB), 256, 0, stream>>>(y, codewords, scale,
                                                scratch, ppb);
  k_vred<<<NB * KD / (256 * 4), 256, 0, stream>>>(scratch, v, npart);
  k_cls<<<NCLASS / 8, 256, 0, stream>>>(v, cls_w, cls_b, out);
}